// Round 6
// baseline (69.030 us; speedup 1.0000x reference)
//
#include <hip/hip_runtime.h>
#include <stdint.h>

// out[m,p] = sum_k f32(bits(x[m,k]) + bits(weight[p,k]) - OFFSET) + bias[p]
// m=256, n=512, p=512. Pure VALU workload (uint add on bit patterns -> no MFMA).
//
// R11 = R10 + eighth-granular ramp-in + own-partial reduction.
//  R10 post-mortem (63.39, -0.69 as predicted): staging exposure converts
//  ~1:1 into wall time. Remaining itemized overhead above the 4096-cyc VALU
//  floor: initial q0 exposure ~585 cyc (32KB at ~56B/cyc/CU from L2) and
//  the reduction tail ~250 cyc.
//  R11 changes (all else byte-identical to R10):
//  - ramp-in: stage only C0 = 16KB (dwords 0..63 of q0) before the first
//    barrier (~293 cyc exposed), then C1 = 16KB hidden under compute(C0),
//    then quarters q1..q3 exactly as R10. Quarter-0 uses 16-dword k-stripes
//    (wave ks owns granules e*16 + ks*4 + j) so every chunk contains all 4
//    stripes and every wave can compute after each barrier. Read slot =
//    (e*16+ks*4+j)^(lane&7): 8 distinct bank-quads, 8 lanes/quad = same
//    minimum-aliasing family R5 measured at SQ_LDS_BANK_CONFLICT==0.
//    Eighth ds_writes: per 16-lane segment slots are a bijection of 0..15
//    -> uniform quad distribution, conflict-free. +1 barrier (~50 cyc).
//  - own-partial reduction: reader wave (ks,mq) takes output row mq*4+ks,
//    whose ks-partial it already holds in acc[ks] -> 3 Red writes + 3 reads
//    instead of 4+4.
//  Model: exposure 585->293, tail -40, +1 barrier => ~-230 cyc ~ -0.1us.
//
// Measurement context: ~60us of dur_us is fixed harness cost (268MB ws
// re-poison = 40us at 84% HBM peak). Controllable = this one kernel
// (~2.0-2.2us vs 1.71us VALU floor).

#define OFFSET_FP32 1064828928u

constexpr int M = 256;
constexpr int N = 512;
constexpr int P = 512;

constexpr int BM = 8;    // m rows per block
constexpr int BP = 64;   // p cols per block
constexpr int TM = 4;    // m rows per thread
constexpr int NQ = 4;    // k quarters
constexpr int QK = 128;  // dwords per quarter per row

__global__ __launch_bounds__(512) void lmul_linear_kernel(
    const uint32_t* __restrict__ xb,   // [M][N] bit patterns of x
    const uint32_t* __restrict__ wb,   // [P][N] bit patterns of weight
    const float*    __restrict__ bias, // [P]
    float*          __restrict__ out)  // [M][P]
{
    __shared__ uint32_t Bs[NQ][BP][QK];   // 128 KB, quarter-major
    __shared__ float    Red[4][BM][BP];   // 8 KB k-group partials

    const int tid  = threadIdx.x;
    const int lane = tid & 63;                                     // = p_local
    const int wq   = __builtin_amdgcn_readfirstlane(tid >> 6);     // wave 0..7
    const int ks   = wq & 3;   // k-group
    const int mq   = wq >> 2;  // row half

    const int p0 = blockIdx.y * BP;
    const int m0 = blockIdx.x * BM + mq * TM;

    // ---------- quarter staging (q = 1..3), identical to R10 ----------
    const int g    = lane & 31;   // 16B granule within a 512B row-quarter
    const int rsel = lane >> 5;   // 2 rows per load instr

    auto qload = [&](int q, uint4* r) {
        #pragma unroll
        for (int i = 0; i < 4; ++i) {
            const int row = wq * 8 + i * 2 + rsel;
            r[i] = *(const uint4*)(wb + (size_t)(p0 + row) * N + q * QK + g * 4);
        }
    };
    auto qwrite1 = [&](int q, uint4 v, int i) {   // fold + swizzled write
        const int row = wq * 8 + i * 2 + rsel;
        v.x -= OFFSET_FP32; v.y -= OFFSET_FP32;
        v.z -= OFFSET_FP32; v.w -= OFFSET_FP32;
        *(uint4*)&Bs[q][row][(g ^ (row & 7)) * 4] = v;
    };

    // ---------- eighth staging (chunks C0/C1 inside quarter 0) ----------
    const int ge    = lane & 15;  // granule within a 256B row-eighth
    const int ersel = lane >> 4;  // 4 rows per load instr

    auto eload = [&](int e, uint4* r) {
        #pragma unroll
        for (int i = 0; i < 2; ++i) {
            const int row = wq * 8 + i * 4 + ersel;
            r[i] = *(const uint4*)(wb + (size_t)(p0 + row) * N + e * 64 + ge * 4);
        }
    };
    auto ewrite1 = [&](int e, uint4 v, int i) {
        const int row = wq * 8 + i * 4 + ersel;
        const int G   = e * 16 + ge;              // logical granule in q0 row
        v.x -= OFFSET_FP32; v.y -= OFFSET_FP32;
        v.z -= OFFSET_FP32; v.w -= OFFSET_FP32;
        *(uint4*)&Bs[0][row][(G ^ (row & 7)) * 4] = v;
    };

    float acc[TM][4] = {};
    const int rot = lane & 7;

    const uint32_t* xr0 = xb + (size_t)(m0 + 0) * N;
    const uint32_t* xr1 = xb + (size_t)(m0 + 1) * N;
    const uint32_t* xr2 = xb + (size_t)(m0 + 2) * N;
    const uint32_t* xr3 = xb + (size_t)(m0 + 3) * N;

    // one accumulate step: granule slot (pre-swizzled) + x dword offset
    auto step = [&](const uint32_t* bq, int slot, int xoff) {
        const uint4 b  = *(const uint4*)&bq[slot * 4];
        const uint4 a0 = *(const uint4*)(xr0 + xoff);  // uniform -> scalar path
        const uint4 a1 = *(const uint4*)(xr1 + xoff);
        const uint4 a2 = *(const uint4*)(xr2 + xoff);
        const uint4 a3 = *(const uint4*)(xr3 + xoff);
        acc[0][0] += __uint_as_float(a0.x + b.x);
        acc[0][1] += __uint_as_float(a0.y + b.y);
        acc[0][2] += __uint_as_float(a0.z + b.z);
        acc[0][3] += __uint_as_float(a0.w + b.w);
        acc[1][0] += __uint_as_float(a1.x + b.x);
        acc[1][1] += __uint_as_float(a1.y + b.y);
        acc[1][2] += __uint_as_float(a1.z + b.z);
        acc[1][3] += __uint_as_float(a1.w + b.w);
        acc[2][0] += __uint_as_float(a2.x + b.x);
        acc[2][1] += __uint_as_float(a2.y + b.y);
        acc[2][2] += __uint_as_float(a2.z + b.z);
        acc[2][3] += __uint_as_float(a2.w + b.w);
        acc[3][0] += __uint_as_float(a3.x + b.x);
        acc[3][1] += __uint_as_float(a3.y + b.y);
        acc[3][2] += __uint_as_float(a3.z + b.z);
        acc[3][3] += __uint_as_float(a3.w + b.w);
    };

    // eighth compute: 4 steps over 16-dword stripe; optional feed writes
    auto compute_e = [&](int e, int feedmode, uint4* r) {
        const uint32_t* bq = &Bs[0][lane][0];
        #pragma unroll
        for (int j = 0; j < 4; ++j) {
            step(bq, (e * 16 + ks * 4 + j) ^ rot, e * 64 + ks * 16 + j * 4);
            if (feedmode == 1 && j >= 2) ewrite1(1, r[j - 2], j - 2);  // C1
            if (feedmode == 2) qwrite1(1, r[j], j);                    // q1
        }
    };

    // quarter compute: 8 steps over 32-dword stripe (R10 pattern)
    auto compute_q = [&](int q, bool feed, int qn, uint4* r) {
        const uint32_t* bq = &Bs[q][lane][0];
        #pragma unroll
        for (int j = 0; j < 8; ++j) {
            step(bq, ks * 8 + (j ^ rot), q * QK + ks * 32 + j * 4);
            if (feed && (j & 1)) qwrite1(qn, r[j >> 1], j >> 1);
        }
    };

    // LDS-visibility-only barrier: drain lgkm but NOT in-flight wave-private
    // global staging loads (vmcnt).
    auto lds_barrier = [&]() {
        asm volatile("s_waitcnt lgkmcnt(0)" ::: "memory");
        __builtin_amdgcn_s_barrier();
        __builtin_amdgcn_sched_barrier(0);
    };

    uint4 ea[2], eb[2], ra[4], rb[4];
    eload(0, ea);
    ewrite1(0, ea[0], 0);      // vmcnt waits here (only 16KB/CU exposed)
    ewrite1(0, ea[1], 1);
    eload(1, eb);              // C1 in flight
    qload(1, ra);              // q1 in flight
    lds_barrier();             // C0 visible

    qload(2, rb);
    compute_e(0, 1, eb);       // C1 writes at j=2,3 (data ~300cyc old)
    lds_barrier();             // C1 visible

    compute_e(1, 2, ra);       // q1 writes, 1/step (data ~300-650cyc old)
    lds_barrier();             // q1 visible

    qload(3, ra);              // ra free again
    compute_q(1, true, 2, rb);
    lds_barrier();             // q2 visible

    compute_q(2, true, 3, ra);
    lds_barrier();             // q3 visible

    compute_q(3, false, 0, nullptr);

    // ---- own-partial reduction: wave (ks,mq) reads back row mq*4+ks,
    //      for which it holds the ks-partial in registers -> 3w + 3r ----
    #pragma unroll
    for (int r = 0; r < TM; ++r) {
        if (r != ks)   // ks is wave-uniform -> uniform branch
            Red[ks][mq * TM + r][lane] =
                (acc[r][0] + acc[r][1]) + (acc[r][2] + acc[r][3]);
    }
    lds_barrier();

    const int Rrow = mq * TM + ks;    // this wave's output row (local)
    float s = (acc[ks][0] + acc[ks][1]) + (acc[ks][2] + acc[ks][3]);
    #pragma unroll
    for (int k2 = 0; k2 < 4; ++k2)
        if (k2 != ks) s += Red[k2][Rrow][lane];

    const int p = p0 + lane;
    out[(size_t)(blockIdx.x * BM + Rrow) * P + p] = s + bias[p];
}

extern "C" void kernel_launch(void* const* d_in, const int* in_sizes, int n_in,
                              void* d_out, int out_size, void* d_ws, size_t ws_size,
                              hipStream_t stream) {
    const uint32_t* xb   = (const uint32_t*)d_in[0];  // x: (256,512) f32 bits
    const uint32_t* wb   = (const uint32_t*)d_in[1];  // weight: (512,512) f32 bits
    const float*    bias = (const float*)d_in[2];     // (512,)
    float*          out  = (float*)d_out;             // (256,512) f32

    // single dispatch: every output written exactly once by its owning block
    dim3 grid(M / BM, P / BP);  // (32, 8) = 256 blocks = 1 per CU
    dim3 block(512);            // 8 waves = 2 waves/SIMD
    lmul_linear_kernel<<<grid, block, 0, stream>>>(xb, wb, bias, out);
}

// Round 7
// 63.896 us; speedup vs baseline: 1.0803x; 1.0803x over previous
//
#include <hip/hip_runtime.h>
#include <stdint.h>

// out[m,p] = sum_k f32(bits(x[m,k]) + bits(weight[p,k]) - OFFSET) + bias[p]
// m=256, n=512, p=512. Pure VALU workload (uint add on bit patterns -> no MFMA).
//
// R12 = byte-for-byte revert to R10 (measured best: 63.39us).
//  R11 post-mortem (+5.6us, predicted -0.1): eighth-granular ramp-in grew
//  peak live staging state 8->12 uint4 buffers + extra barrier + eighth-
//  phase addressing; kernel ~tripled (R8-signature: pressure-driven spill /
//  schedule serialization). Reverted. Lesson: remaining itemized overhead
//  (~250cyc = 0.1us) is below the harness noise band (+-0.5us) -- no more
//  restructuring is justified.
//  R10 structure (kept verbatim):
//  - single dispatch, no memset, no atomics; grid 32x8 = 256 blocks = 1/CU,
//    512 thr = 8 waves = 2 waves/SIMD. Block owns its 8x64 output tile.
//  - wave-level 4-way k-split (ks=wq&3, mq=wq>>2), combined via an 8KB LDS
//    reduction + one plain coalesced store.
//  - Bs[4][64][128] quarter-major; only q0 staged before the first barrier
//    (~585cyc exposed); q(n+1) global loads issued at top of compute(n-1),
//    its ds_writes interleaved INTO compute(n) (one per odd j-step) against
//    a buffer nobody reads -> mid-kernel staging exposure ~0.
//  - reg-staging with OFFSET folded in VGPRs at write time; inner loop is
//    exactly 16 v_add_u32 + 16 v_add_f32 per step (2 VALU/element floor),
//    x rides the wave-uniform scalar path (s_load_dwordx4).
//  - swizzle family measured at SQ_LDS_BANK_CONFLICT==0 (R5/R7/R10): row r
//    granule g stored at g^(r&7); writes are a permutation of a contiguous
//    1KB segment; reads hit 8 distinct granules per 8 lanes.
//  - barriers are s_waitcnt lgkmcnt(0) + s_barrier (LDS-visibility only) so
//    in-flight wave-private global staging loads are never drained.
//  Accounting: 4096cyc VALU floor (1.71us) + ~585cyc q0 exposure + ~300cyc
//  tails/barriers ~ 2.1us kernel; residual vs floor is below harness noise.
//
// Measurement context: ~60us of dur_us is fixed harness cost (268MB ws
// re-poison = 40us at 84% HBM peak). Controllable = this one kernel.

#define OFFSET_FP32 1064828928u

constexpr int M = 256;
constexpr int N = 512;
constexpr int P = 512;

constexpr int BM = 8;    // m rows per block
constexpr int BP = 64;   // p cols per block
constexpr int TM = 4;    // m rows per thread
constexpr int NQ = 4;    // k quarters
constexpr int QK = 128;  // dwords per quarter per row

__global__ __launch_bounds__(512) void lmul_linear_kernel(
    const uint32_t* __restrict__ xb,   // [M][N] bit patterns of x
    const uint32_t* __restrict__ wb,   // [P][N] bit patterns of weight
    const float*    __restrict__ bias, // [P]
    float*          __restrict__ out)  // [M][P]
{
    __shared__ uint32_t Bs[NQ][BP][QK];   // 128 KB, quarter-major
    __shared__ float    Red[4][BM][BP];   // 8 KB k-group partials

    const int tid  = threadIdx.x;
    const int lane = tid & 63;                                     // = p_local
    const int wq   = __builtin_amdgcn_readfirstlane(tid >> 6);     // wave 0..7
    const int ks   = wq & 3;   // k-group
    const int mq   = wq >> 2;  // row half

    const int p0 = blockIdx.y * BP;
    const int m0 = blockIdx.x * BM + mq * TM;

    const int g    = lane & 31;   // 16B granule within a 512B row-quarter
    const int rsel = lane >> 5;   // each wave iter covers 2 rows

    // ---- quarter q: wave wq covers rows wq*8..wq*8+7, 4 iters x 2 rows.
    //      Loads plain coalesced (512B per row-quarter); swizzle applied at
    //      the ds_write address: granule g stored at g^(row&7) -> write is a
    //      permutation of a contiguous 1KB region = conflict-free b128. ----
    auto qload = [&](int q, uint4* r) {
        #pragma unroll
        for (int i = 0; i < 4; ++i) {
            const int row = wq * 8 + i * 2 + rsel;
            r[i] = *(const uint4*)(wb + (size_t)(p0 + row) * N + q * QK + g * 4);
        }
    };
    auto qwrite1 = [&](int q, uint4 v, int i) {   // one fold+write
        const int row = wq * 8 + i * 2 + rsel;
        v.x -= OFFSET_FP32; v.y -= OFFSET_FP32;
        v.z -= OFFSET_FP32; v.w -= OFFSET_FP32;
        *(uint4*)&Bs[q][row][(g ^ (row & 7)) * 4] = v;
    };

    float acc[TM][4] = {};
    const int rot = lane & 7;

    const uint32_t* xr0 = xb + (size_t)(m0 + 0) * N;
    const uint32_t* xr1 = xb + (size_t)(m0 + 1) * N;
    const uint32_t* xr2 = xb + (size_t)(m0 + 2) * N;
    const uint32_t* xr3 = xb + (size_t)(m0 + 3) * N;

    // ---- compute quarter q for this k-group: 8 steps x (1 ds_read_b128 +
    //      4 uniform uint4 s_loads + 32 VALU); if feeding, one ds_write_b128
    //      of quarter qn after each odd step (hidden under the VALU). ----
    auto computeq = [&](int q, bool feed, int qn, uint4* r) {
        const uint32_t* brow = &Bs[q][lane][ks * 32];
        const int xoff = q * QK + ks * 32;
        #pragma unroll
        for (int j = 0; j < 8; ++j) {
            const uint4 b  = *(const uint4*)&brow[(j ^ rot) * 4];
            const uint4 a0 = *(const uint4*)(xr0 + xoff + j * 4);  // scalar path
            const uint4 a1 = *(const uint4*)(xr1 + xoff + j * 4);
            const uint4 a2 = *(const uint4*)(xr2 + xoff + j * 4);
            const uint4 a3 = *(const uint4*)(xr3 + xoff + j * 4);
            acc[0][0] += __uint_as_float(a0.x + b.x);
            acc[0][1] += __uint_as_float(a0.y + b.y);
            acc[0][2] += __uint_as_float(a0.z + b.z);
            acc[0][3] += __uint_as_float(a0.w + b.w);
            acc[1][0] += __uint_as_float(a1.x + b.x);
            acc[1][1] += __uint_as_float(a1.y + b.y);
            acc[1][2] += __uint_as_float(a1.z + b.z);
            acc[1][3] += __uint_as_float(a1.w + b.w);
            acc[2][0] += __uint_as_float(a2.x + b.x);
            acc[2][1] += __uint_as_float(a2.y + b.y);
            acc[2][2] += __uint_as_float(a2.z + b.z);
            acc[2][3] += __uint_as_float(a2.w + b.w);
            acc[3][0] += __uint_as_float(a3.x + b.x);
            acc[3][1] += __uint_as_float(a3.y + b.y);
            acc[3][2] += __uint_as_float(a3.z + b.z);
            acc[3][3] += __uint_as_float(a3.w + b.w);
            if (feed && (j & 1)) qwrite1(qn, r[j >> 1], j >> 1);
        }
    };

    // LDS-visibility-only barrier: drain lgkm (ds + smem) but NOT the
    // in-flight wave-private global staging loads (vmcnt).
    auto lds_barrier = [&]() {
        asm volatile("s_waitcnt lgkmcnt(0)" ::: "memory");
        __builtin_amdgcn_s_barrier();
        __builtin_amdgcn_sched_barrier(0);
    };

    uint4 ra[4], rb[4];
    qload(0, ra);
    #pragma unroll
    for (int i = 0; i < 4; ++i) qwrite1(0, ra[i], i);  // vmcnt waits here
    qload(1, rb);              // q1 in flight; delivery rides under compute(0)
    lds_barrier();             // q0 visible

    qload(2, ra);              // waitless issue
    computeq(0, true, 1, rb);  // q1 writes interleaved, hidden
    lds_barrier();             // q1 visible

    qload(3, rb);
    computeq(1, true, 2, ra);
    lds_barrier();             // q2 visible

    computeq(2, true, 3, rb);
    lds_barrier();             // q3 visible

    computeq(3, false, 0, nullptr);

    // ---- per-output 4-way k-group reduction in LDS, then one plain store ----
    #pragma unroll
    for (int r = 0; r < TM; ++r)
        Red[ks][mq * TM + r][lane] =
            (acc[r][0] + acc[r][1]) + (acc[r][2] + acc[r][3]);
    __syncthreads();

    const int rr = tid >> 6;          // 0..7: local output row
    const int p  = p0 + lane;
    const float s = (Red[0][rr][lane] + Red[1][rr][lane])
                  + (Red[2][rr][lane] + Red[3][rr][lane]);
    out[(size_t)(blockIdx.x * BM + rr) * P + p] = s + bias[p];
}

extern "C" void kernel_launch(void* const* d_in, const int* in_sizes, int n_in,
                              void* d_out, int out_size, void* d_ws, size_t ws_size,
                              hipStream_t stream) {
    const uint32_t* xb   = (const uint32_t*)d_in[0];  // x: (256,512) f32 bits
    const uint32_t* wb   = (const uint32_t*)d_in[1];  // weight: (512,512) f32 bits
    const float*    bias = (const float*)d_in[2];     // (512,)
    float*          out  = (float*)d_out;             // (256,512) f32

    // single dispatch: every output written exactly once by its owning block
    dim3 grid(M / BM, P / BP);  // (32, 8) = 256 blocks = 1 per CU
    dim3 block(512);            // 8 waves = 2 waves/SIMD
    lmul_linear_kernel<<<grid, block, 0, stream>>>(xb, wb, bias, out);
}